// Round 8
// baseline (552.028 us; speedup 1.0000x reference)
//
#include <hip/hip_runtime.h>
#include <hip/hip_bf16.h>

#define NN 6144
#define DD 128
#define INV_TAU 10.0f

typedef __attribute__((ext_vector_type(4))) float f32x4;
typedef __attribute__((ext_vector_type(8))) short s16x8;

// ---------------- Kernel 1: L2 normalize -> fp32 + bf16 copies -------------
__global__ void k_normalize(const float* __restrict__ embF,
                            const float* __restrict__ embM,
                            const float* __restrict__ embP,
                            float* __restrict__ Fn, float* __restrict__ Mn,
                            float* __restrict__ Pn,
                            __hip_bfloat16* __restrict__ Fnb,
                            __hip_bfloat16* __restrict__ Mnb,
                            __hip_bfloat16* __restrict__ Pnb) {
    int which = blockIdx.y;
    const float* src = which == 0 ? embF : (which == 1 ? embM : embP);
    float* dst = which == 0 ? Fn : (which == 1 ? Mn : Pn);
    __hip_bfloat16* dstb = which == 0 ? Fnb : (which == 1 ? Mnb : Pnb);
    int wave = threadIdx.x >> 6, lane = threadIdx.x & 63;
    int row = blockIdx.x * 4 + wave;
    float2 v = reinterpret_cast<const float2*>(src + (size_t)row * DD)[lane];
    float s = v.x * v.x + v.y * v.y;
#pragma unroll
    for (int m = 1; m <= 32; m <<= 1) s += __shfl_xor(s, m);
    float inv = 1.0f / fmaxf(sqrtf(s), 1e-12f);
    float2 o; o.x = v.x * inv; o.y = v.y * inv;
    reinterpret_cast<float2*>(dst + (size_t)row * DD)[lane] = o;
    __hip_bfloat162 ob;
    ob.x = __float2bfloat16(o.x);
    ob.y = __float2bfloat16(o.y);
    reinterpret_cast<__hip_bfloat162*>(dstb + (size_t)row * DD)[lane] = ob;
}

// ------- Kernel 2: adjacency stream -> compact nnz lists + counts ----------
// One wave per (row, half). 6 explicitly-named float4 loads per batch force
// the compiler to keep 6 loads in flight (R7: VGPR=16 => serial round-trips).
__global__ __launch_bounds__(256) void k_scan(
        const float* __restrict__ FM_adj, const float* __restrict__ FP_adj,
        int* __restrict__ nzbuf, int* __restrict__ nzcnt,
        float* __restrict__ cntF, float* __restrict__ cntP) {
    __shared__ int lbuf[4][64 * 12];                 // 12 KB
    const int h = blockIdx.y;
    const float* adj = h ? FP_adj : FM_adj;
    const int w = threadIdx.x >> 6, lane = threadIdx.x & 63;
    const int row = blockIdx.x * 4 + w;
    const float4* rp = reinterpret_cast<const float4*>(adj + (size_t)row * NN);
    int* mybuf = &lbuf[w][lane * 12];
    int mycnt = 0;
    // 24 float4 per lane = 4 batches x 6 explicit loads
    for (int it = 0; it < 4; ++it) {
        const int c0 = (it * 6) * 64 + lane;
        float4 v0 = rp[c0];
        float4 v1 = rp[c0 + 64];
        float4 v2 = rp[c0 + 128];
        float4 v3 = rp[c0 + 192];
        float4 v4 = rp[c0 + 256];
        float4 v5 = rp[c0 + 320];
        float4 vv[6] = {v0, v1, v2, v3, v4, v5};
#pragma unroll
        for (int u = 0; u < 6; ++u) {
            int colbase = (it * 6 + u) * 256 + lane * 4;
            if (vv[u].x != 0.f) { if (mycnt < 12) mybuf[mycnt] = colbase;     mycnt++; }
            if (vv[u].y != 0.f) { if (mycnt < 12) mybuf[mycnt] = colbase + 1; mycnt++; }
            if (vv[u].z != 0.f) { if (mycnt < 12) mybuf[mycnt] = colbase + 2; mycnt++; }
            if (vv[u].w != 0.f) { if (mycnt < 12) mybuf[mycnt] = colbase + 3; mycnt++; }
        }
    }
    int cnt = mycnt < 12 ? mycnt : 12;               // P(lane>12 nnz) ~ 0
    // exclusive prefix over 64 lanes (order within list is irrelevant)
    int x = cnt;
#pragma unroll
    for (int d = 1; d < 64; d <<= 1) {
        int y = __shfl_up(x, d);
        if (lane >= d) x += y;
    }
    int pref = x - cnt;
    int totc = __shfl(x, 63);
    int t = mycnt;                                   // true row count
#pragma unroll
    for (int msk = 1; msk <= 32; msk <<= 1) t += __shfl_xor(t, msk);
    const int base = (h * NN + row) << 7;
    for (int i = 0; i < cnt; ++i) {
        int slot = pref + i;
        if (slot < 128) nzbuf[base + slot] = mybuf[i];
    }
    if (lane == 0) {
        nzcnt[h * NN + row] = totc < 128 ? totc : 128;
        (h ? cntP : cntF)[row] = (float)t;
    }
}

// ------- Kernel 3: dense exp row-sum via bf16 MFMA ------------------------
// grid (96, 8, 2), block 256 = 4 waves; wave = 16 rows x 768-col strip.
// No LDS, no barriers: explicit register double-buffer of the next B tile
// so L2 latency hides under MFMA+exp of the current tile.
__global__ __launch_bounds__(256) void k_dense(
        const __hip_bfloat16* __restrict__ Fnb,
        const __hip_bfloat16* __restrict__ Mnb,
        const __hip_bfloat16* __restrict__ Pnb,
        float* __restrict__ FMtot, float* __restrict__ FPtot) {
    const int half = blockIdx.z;
    const __hip_bfloat16* Bnb = half ? Pnb : Mnb;
    float* TOT = half ? FPtot : FMtot;
    const int tid = threadIdx.x;
    const int w = tid >> 6, lane = tid & 63;
    const int m = lane & 15, q = lane >> 4;
    const int rb = blockIdx.x * 64 + w * 16;
    const int j0 = blockIdx.y * (NN / 8), jend = j0 + NN / 8;

    // loop-invariant A fragments: lane holds A[m][k=q*8+j], k-step 32
    s16x8 a[4];
#pragma unroll
    for (int ks = 0; ks < 4; ++ks)
        a[ks] = *reinterpret_cast<const s16x8*>(
            Fnb + (size_t)(rb + m) * DD + ks * 32 + q * 8);

    s16x8 cur[2][4], nxt[2][4];
#pragma unroll
    for (int t = 0; t < 2; ++t) {
        const __hip_bfloat16* bp = Bnb + (size_t)(j0 + t * 16 + m) * DD + q * 8;
#pragma unroll
        for (int ks = 0; ks < 4; ++ks)
            cur[t][ks] = *reinterpret_cast<const s16x8*>(bp + ks * 32);
    }

    float tot[4] = {0.f, 0.f, 0.f, 0.f};
    for (int jc = j0; jc < jend; jc += 32) {
        int jn = (jc + 32 < jend) ? jc + 32 : j0;    // wrap: harmless reload
#pragma unroll
        for (int t = 0; t < 2; ++t) {
            const __hip_bfloat16* bp = Bnb + (size_t)(jn + t * 16 + m) * DD + q * 8;
#pragma unroll
            for (int ks = 0; ks < 4; ++ks)
                nxt[t][ks] = *reinterpret_cast<const s16x8*>(bp + ks * 32);
        }
#pragma unroll
        for (int t = 0; t < 2; ++t) {
            f32x4 acc = {0.f, 0.f, 0.f, 0.f};
#pragma unroll
            for (int ks = 0; ks < 4; ++ks)
                acc = __builtin_amdgcn_mfma_f32_16x16x32_bf16(a[ks], cur[t][ks],
                                                              acc, 0, 0, 0);
#pragma unroll
            for (int r = 0; r < 4; ++r)
                tot[r] += __expf(acc[r] * INV_TAU);
        }
#pragma unroll
        for (int t = 0; t < 2; ++t)
#pragma unroll
            for (int ks = 0; ks < 4; ++ks)
                cur[t][ks] = nxt[t][ks];
    }
#pragma unroll
    for (int msk = 1; msk <= 8; msk <<= 1)
#pragma unroll
        for (int r = 0; r < 4; ++r) tot[r] += __shfl_xor(tot[r], msk);
    if (m == 0)
#pragma unroll
        for (int r = 0; r < 4; ++r)
            atomicAdd(&TOT[rb + q * 4 + r], tot[r]);
}

// ------- Kernel 4: gather repr (raw emb) + exact fp32 pos ------------------
__global__ void k_gather(const float* __restrict__ embM,
                         const float* __restrict__ embP,
                         const float* __restrict__ Fn,
                         const float* __restrict__ Mn,
                         const float* __restrict__ Pn,
                         const int* __restrict__ nzbuf,
                         const int* __restrict__ nzcnt,
                         const float* __restrict__ cntF,
                         const float* __restrict__ cntP,
                         float* __restrict__ feat,
                         float* __restrict__ FMpos, float* __restrict__ FPpos) {
    __shared__ float FnS[DD];
    __shared__ int listS[128];
    __shared__ float posS[2];
    const int row = blockIdx.x, h = blockIdx.y;
    const int tid = threadIdx.x;            // 0..127 = output dim
    const int wv = tid >> 6, lane = tid & 63;
    const float* embX = h ? embP : embM;
    const float* Bn = h ? Pn : Mn;
    FnS[tid] = Fn[(size_t)row * DD + tid];
    int K = nzcnt[h * NN + row];
    if (tid < K) listS[tid] = nzbuf[((h * NN + row) << 7) + tid];
    __syncthreads();
    // repr: 4-way ILP
    float a0 = 0.f, a1 = 0.f, a2 = 0.f, a3 = 0.f;
    int k = 0;
    for (; k + 4 <= K; k += 4) {
        int i0 = listS[k], i1 = listS[k + 1], i2 = listS[k + 2], i3 = listS[k + 3];
        a0 += embX[(size_t)i0 * DD + tid];
        a1 += embX[(size_t)i1 * DD + tid];
        a2 += embX[(size_t)i2 * DD + tid];
        a3 += embX[(size_t)i3 * DD + tid];
    }
    for (; k < K; ++k) a0 += embX[(size_t)listS[k] * DD + tid];
    float cn = (h ? cntP : cntF)[row];
    feat[(size_t)row * (2 * DD) + h * DD + tid] =
        ((a0 + a1) + (a2 + a3)) / fmaxf(cn, 1.0f);
    // pos: wave-cooperative fp32 dot + exp per neighbor
    float2 f = reinterpret_cast<const float2*>(FnS)[lane];
    float wsum = 0.f;
    for (int kk = wv; kk < K; kk += 2) {
        int j = listS[kk];
        float2 b = reinterpret_cast<const float2*>(Bn + (size_t)j * DD)[lane];
        float d = f.x * b.x + f.y * b.y;
#pragma unroll
        for (int msk = 1; msk <= 32; msk <<= 1) d += __shfl_xor(d, msk);
        wsum += __expf(d * INV_TAU);
    }
    if (lane == 0) posS[wv] = wsum;
    __syncthreads();
    if (tid == 0) (h ? FPpos : FMpos)[row] = posS[0] + posS[1];
}

// ------- Kernel 5: MLP hidden + logits (8 rows / 256-thread block) ---------
__global__ __launch_bounds__(256) void k_mlp1(
        const float* __restrict__ feat,
        const float* __restrict__ W1, const float* __restrict__ b1,
        const float* __restrict__ W2, const float* __restrict__ b2,
        float* __restrict__ z) {
    __shared__ float featS[8][2 * DD];              // 8 KB
    __shared__ float red[4][4][2];
    const int tid = threadIdx.x;
    const int g = tid >> 7, d = tid & 127;
    const int wv = tid >> 6, lane = tid & 63;
    const int row0 = blockIdx.x * 8;
    for (int idx = tid; idx < 8 * 2 * DD; idx += 256)
        featS[idx >> 8][idx & 255] = feat[(size_t)row0 * (2 * DD) + idx];
    __syncthreads();
    float bb = b1[d];
    float acc0 = bb, acc1 = bb, acc2 = bb, acc3 = bb;
    const float* fS = &featS[g * 4][0];
#pragma unroll 4
    for (int c = 0; c < 2 * DD; ++c) {
        float w1v = W1[c * DD + d];
        acc0 = fmaf(fS[0 * 256 + c], w1v, acc0);
        acc1 = fmaf(fS[1 * 256 + c], w1v, acc1);
        acc2 = fmaf(fS[2 * 256 + c], w1v, acc2);
        acc3 = fmaf(fS[3 * 256 + c], w1v, acc3);
    }
    float w20 = W2[2 * d], w21 = W2[2 * d + 1];
    float hr[4] = {fmaxf(acc0, 0.f), fmaxf(acc1, 0.f),
                   fmaxf(acc2, 0.f), fmaxf(acc3, 0.f)};
#pragma unroll
    for (int r = 0; r < 4; ++r) {
        float p0 = hr[r] * w20, p1 = hr[r] * w21;
#pragma unroll
        for (int msk = 1; msk <= 32; msk <<= 1) {
            p0 += __shfl_xor(p0, msk);
            p1 += __shfl_xor(p1, msk);
        }
        if (lane == 0) { red[wv][r][0] = p0; red[wv][r][1] = p1; }
    }
    __syncthreads();
    if (tid < 8) {
        int g2 = tid >> 2, r = tid & 3;
        float z0 = red[2 * g2][r][0] + red[2 * g2 + 1][r][0] + b2[0];
        float z1 = red[2 * g2][r][1] + red[2 * g2 + 1][r][1] + b2[1];
        z[(row0 + tid) * 2 + 0] = z0;
        z[(row0 + tid) * 2 + 1] = z1;
    }
}

// ------- Kernel 6: softmax weights + loss (one atomic per block) -----------
__global__ void k_loss(const float* __restrict__ z,
                       const float* __restrict__ FMpos, const float* __restrict__ FPpos,
                       const float* __restrict__ FMtot, const float* __restrict__ FPtot,
                       const float* __restrict__ cntF, const float* __restrict__ cntP,
                       float* __restrict__ out) {
    __shared__ float red[4];
    const int tid = threadIdx.x;
    const int lane = tid & 63, wv = tid >> 6;
    const int row = blockIdx.x * 256 + tid;
    float z0 = z[row * 2], z1 = z[row * 2 + 1];
    float mx = fmaxf(z0, z1);
    float e0 = expf(z0 - mx), e1 = expf(z1 - mx);
    float inv = 1.0f / (e0 + e1);
    float w0 = e0 * inv, w1 = e1 * inv;
    out[1 + row * 2 + 0] = w0;
    out[1 + row * 2 + 1] = w1;
    float wp = w0 * FMpos[row] + w1 * FPpos[row];
    float wn = w0 * (FMtot[row] - FMpos[row]) + w1 * (FPtot[row] - FPpos[row]);
    float nei = fmaxf(cntF[row] + cntP[row], 1.0f);
    float ratio = wp / (wp + wn) / nei;
    ratio = fmaxf(ratio, 1e-10f);
    float term = -logf(ratio);
#pragma unroll
    for (int msk = 1; msk <= 32; msk <<= 1) term += __shfl_xor(term, msk);
    if (lane == 0) red[wv] = term;
    __syncthreads();
    if (tid == 0)
        atomicAdd(out, (red[0] + red[1] + red[2] + red[3]) * (1.0f / NN));
}

extern "C" void kernel_launch(void* const* d_in, const int* in_sizes, int n_in,
                              void* d_out, int out_size, void* d_ws, size_t ws_size,
                              hipStream_t stream) {
    const float* embF   = (const float*)d_in[0];
    const float* embM   = (const float*)d_in[1];
    const float* embP   = (const float*)d_in[2];
    const float* FM_adj = (const float*)d_in[3];
    const float* FP_adj = (const float*)d_in[4];
    const float* W1     = (const float*)d_in[5];
    const float* b1     = (const float*)d_in[6];
    const float* W2     = (const float*)d_in[7];
    const float* b2     = (const float*)d_in[8];
    float* out = (float*)d_out;

    float* ws = (float*)d_ws;
    float* FMtot = ws;                       // N  (atomic -> zeroed)
    float* FPtot = FMtot + NN;               // N  (atomic -> zeroed)
    float* FMpos = FPtot + NN;               // N
    float* FPpos = FMpos + NN;               // N
    float* cntF  = FPpos + NN;               // N
    float* cntP  = cntF + NN;                // N
    float* feat  = cntP + NN;                // N*2D
    float* zbuf  = feat + (size_t)NN * 2 * DD;   // N*2
    float* Fn    = zbuf + 2 * NN;            // N*D fp32 normalized
    float* Mn    = Fn + (size_t)NN * DD;
    float* Pn    = Mn + (size_t)NN * DD;
    __hip_bfloat16* Fnb = (__hip_bfloat16*)(Pn + (size_t)NN * DD);
    __hip_bfloat16* Mnb = Fnb + (size_t)NN * DD;
    __hip_bfloat16* Pnb = Mnb + (size_t)NN * DD;
    int* nzbuf = (int*)(Pnb + (size_t)NN * DD);  // 2*N*128 ints
    int* nzcnt = nzbuf + 2 * (size_t)NN * 128;   // 2*N ints

    hipMemsetAsync(FMtot, 0, 2 * NN * sizeof(float), stream);
    hipMemsetAsync(d_out, 0, sizeof(float), stream);

    k_normalize<<<dim3(NN / 4, 3), 256, 0, stream>>>(embF, embM, embP,
                                                     Fn, Mn, Pn, Fnb, Mnb, Pnb);
    k_scan<<<dim3(NN / 4, 2), 256, 0, stream>>>(FM_adj, FP_adj,
                                                nzbuf, nzcnt, cntF, cntP);
    k_dense<<<dim3(NN / 64, 8, 2), 256, 0, stream>>>(Fnb, Mnb, Pnb, FMtot, FPtot);
    k_gather<<<dim3(NN, 2), 128, 0, stream>>>(embM, embP, Fn, Mn, Pn,
                                              nzbuf, nzcnt, cntF, cntP,
                                              feat, FMpos, FPpos);
    k_mlp1<<<dim3(NN / 8), 256, 0, stream>>>(feat, W1, b1, W2, b2, zbuf);
    k_loss<<<dim3(NN / 256), 256, 0, stream>>>(zbuf, FMpos, FPpos, FMtot, FPtot,
                                               cntF, cntP, out);
}

// Round 10
// 449.887 us; speedup vs baseline: 1.2270x; 1.2270x over previous
//
#include <hip/hip_runtime.h>
#include <hip/hip_bf16.h>

#define NN 6144
#define DD 128
#define PBL 136         // padded LDS row stride (bf16 elems) -> balanced banks
#define INV_TAU 10.0f

typedef __attribute__((ext_vector_type(4))) float f32x4;
typedef __attribute__((ext_vector_type(8))) short s16x8;

// ---------------- Kernel 1: L2 normalize -> fp32 Fn, bf16 copies, inv-norms
__global__ void k_normalize(const float* __restrict__ embF,
                            const float* __restrict__ embM,
                            const float* __restrict__ embP,
                            float* __restrict__ Fn,
                            float* __restrict__ rnM, float* __restrict__ rnP,
                            __hip_bfloat16* __restrict__ Fnb,
                            __hip_bfloat16* __restrict__ Mnb,
                            __hip_bfloat16* __restrict__ Pnb) {
    int which = blockIdx.y;
    const float* src = which == 0 ? embF : (which == 1 ? embM : embP);
    __hip_bfloat16* dstb = which == 0 ? Fnb : (which == 1 ? Mnb : Pnb);
    int wave = threadIdx.x >> 6, lane = threadIdx.x & 63;
    int row = blockIdx.x * 4 + wave;
    float2 v = reinterpret_cast<const float2*>(src + (size_t)row * DD)[lane];
    float s = v.x * v.x + v.y * v.y;
#pragma unroll
    for (int m = 1; m <= 32; m <<= 1) s += __shfl_xor(s, m);
    float inv = 1.0f / fmaxf(sqrtf(s), 1e-12f);
    float2 o; o.x = v.x * inv; o.y = v.y * inv;
    if (which == 0)
        reinterpret_cast<float2*>(Fn + (size_t)row * DD)[lane] = o;
    if (lane == 0) {
        if (which == 1) rnM[row] = inv;
        if (which == 2) rnP[row] = inv;
    }
    __hip_bfloat162 ob;
    ob.x = __float2bfloat16(o.x);
    ob.y = __float2bfloat16(o.y);
    reinterpret_cast<__hip_bfloat162*>(dstb + (size_t)row * DD)[lane] = ob;
}

// ------- Kernel 2: adjacency stream -> compact nnz lists + counts ----------
// One wave per (row, half). 8 explicitly-named float4 loads per batch keep
// 8 HBM loads in flight (R7 counter evidence: VGPR=16 => serial, 1.3 TB/s).
__global__ __launch_bounds__(256) void k_scan(
        const float* __restrict__ FM_adj, const float* __restrict__ FP_adj,
        int* __restrict__ nzbuf, int* __restrict__ nzcnt,
        float* __restrict__ cntF, float* __restrict__ cntP) {
    __shared__ int lbuf[4][64 * 12];                 // 12 KB
    const int h = blockIdx.y;
    const float* adj = h ? FP_adj : FM_adj;
    const int w = threadIdx.x >> 6, lane = threadIdx.x & 63;
    const int row = blockIdx.x * 4 + w;
    const float4* rp = reinterpret_cast<const float4*>(adj + (size_t)row * NN);
    int* mybuf = &lbuf[w][lane * 12];
    int mycnt = 0;
    // 24 float4 per lane = 3 batches x 8 explicit loads
    for (int b = 0; b < 3; ++b) {
        const int c0 = b * 8 * 64 + lane;
        float4 v0 = rp[c0];
        float4 v1 = rp[c0 + 64];
        float4 v2 = rp[c0 + 128];
        float4 v3 = rp[c0 + 192];
        float4 v4 = rp[c0 + 256];
        float4 v5 = rp[c0 + 320];
        float4 v6 = rp[c0 + 384];
        float4 v7 = rp[c0 + 448];
        float4 vv[8] = {v0, v1, v2, v3, v4, v5, v6, v7};
#pragma unroll
        for (int u = 0; u < 8; ++u) {
            int colbase = (b * 8 + u) * 256 + lane * 4;
            if (vv[u].x != 0.f) { if (mycnt < 12) mybuf[mycnt] = colbase;     mycnt++; }
            if (vv[u].y != 0.f) { if (mycnt < 12) mybuf[mycnt] = colbase + 1; mycnt++; }
            if (vv[u].z != 0.f) { if (mycnt < 12) mybuf[mycnt] = colbase + 2; mycnt++; }
            if (vv[u].w != 0.f) { if (mycnt < 12) mybuf[mycnt] = colbase + 3; mycnt++; }
        }
    }
    int cnt = mycnt < 12 ? mycnt : 12;               // P(lane>12 nnz) ~ 0
    int x = cnt;                                     // exclusive prefix, 64 lanes
#pragma unroll
    for (int d = 1; d < 64; d <<= 1) {
        int y = __shfl_up(x, d);
        if (lane >= d) x += y;
    }
    int pref = x - cnt;
    int totc = __shfl(x, 63);
    int t = mycnt;                                   // true row count
#pragma unroll
    for (int msk = 1; msk <= 32; msk <<= 1) t += __shfl_xor(t, msk);
    const int base = (h * NN + row) << 7;
    for (int i = 0; i < cnt; ++i) {
        int slot = pref + i;
        if (slot < 128) nzbuf[base + slot] = mybuf[i];
    }
    if (lane == 0) {
        nzcnt[h * NN + row] = totc < 128 ? totc : 128;
        (h ? cntP : cntF)[row] = (float)t;
    }
}

// ------- Kernel 3: dense exp row-sum, LDS-staged B, software-pipelined -----
// grid (48, 8, 2), block 256 = 4 waves; wave owns 32 rows (2 frag groups).
// Per 32-col tile: stage 8KB via regs->LDS (padded rows), issue next tile's
// global loads immediately after the barrier, pin order with asm barrier.
__global__ __launch_bounds__(256) void k_dense(
        const __hip_bfloat16* __restrict__ Fnb,
        const __hip_bfloat16* __restrict__ Mnb,
        const __hip_bfloat16* __restrict__ Pnb,
        float* __restrict__ FMtot, float* __restrict__ FPtot) {
    __shared__ __hip_bfloat16 Bs[32][PBL];           // 8704 B, balanced banks
    const int half = blockIdx.z;
    const __hip_bfloat16* Bnb = half ? Pnb : Mnb;
    float* TOT = half ? FPtot : FMtot;
    const int tid = threadIdx.x;
    const int w = tid >> 6, lane = tid & 63;
    const int m = lane & 15, q = lane >> 4;
    const int rb = blockIdx.x * 128 + w * 32;
    const int j0 = blockIdx.y * (NN / 8);
    const int srow = tid >> 4, scol = (tid & 15) * 8;    // staging store slot

    // loop-invariant A fragments for the wave's 2 row groups
    s16x8 a[2][4];
#pragma unroll
    for (int g = 0; g < 2; ++g)
#pragma unroll
        for (int ks = 0; ks < 4; ++ks)
            a[g][ks] = *reinterpret_cast<const s16x8*>(
                Fnb + (size_t)(rb + g * 16 + m) * DD + ks * 32 + q * 8);

    const float4* gt0 = reinterpret_cast<const float4*>(Bnb + (size_t)j0 * DD);
    float4 s0 = gt0[tid], s1 = gt0[256 + tid];

    float tot[2][4] = {{0.f, 0.f, 0.f, 0.f}, {0.f, 0.f, 0.f, 0.f}};
    for (int it = 0; it < 24; ++it) {
        __syncthreads();                 // previous tile fully consumed
        *reinterpret_cast<float4*>(&Bs[srow][scol]) = s0;       // rows 0..15
        *reinterpret_cast<float4*>(&Bs[16 + srow][scol]) = s1;  // rows 16..31
        __syncthreads();                 // tile visible to all waves
        if (it + 1 < 24) {               // issue next tile's loads EARLY
            const float4* gt = reinterpret_cast<const float4*>(
                Bnb + (size_t)(j0 + (it + 1) * 32) * DD);
            s0 = gt[tid];
            s1 = gt[256 + tid];
        }
        asm volatile("" ::: "memory");   // pin loads before the consume
        s16x8 b[2][4];
#pragma unroll
        for (int t = 0; t < 2; ++t)
#pragma unroll
            for (int ks = 0; ks < 4; ++ks)
                b[t][ks] = *reinterpret_cast<const s16x8*>(
                    &Bs[t * 16 + m][ks * 32 + q * 8]);
#pragma unroll
        for (int g = 0; g < 2; ++g)
#pragma unroll
            for (int t = 0; t < 2; ++t) {
                f32x4 acc = {0.f, 0.f, 0.f, 0.f};
#pragma unroll
                for (int ks = 0; ks < 4; ++ks)
                    acc = __builtin_amdgcn_mfma_f32_16x16x32_bf16(
                        a[g][ks], b[t][ks], acc, 0, 0, 0);
#pragma unroll
                for (int r = 0; r < 4; ++r)
                    tot[g][r] += __expf(acc[r] * INV_TAU);
            }
    }
#pragma unroll
    for (int msk = 1; msk <= 8; msk <<= 1)
#pragma unroll
        for (int g = 0; g < 2; ++g)
#pragma unroll
            for (int r = 0; r < 4; ++r)
                tot[g][r] += __shfl_xor(tot[g][r], msk);
    if (m == 0)
#pragma unroll
        for (int g = 0; g < 2; ++g)
#pragma unroll
            for (int r = 0; r < 4; ++r)
                atomicAdd(&TOT[rb + g * 16 + q * 4 + r], tot[g][r]);
}

// ------- Kernel 4: gather -- repr AND pos from ONE row load per neighbor ---
// Block (row, half), 128 thr = 2 waves. Wave loads a full embX row (float2
// per lane), adds to repr partials, and dots with Fn (x inv-norm) for pos.
__global__ void k_gather(const float* __restrict__ embM,
                         const float* __restrict__ embP,
                         const float* __restrict__ Fn,
                         const float* __restrict__ rnM,
                         const float* __restrict__ rnP,
                         const int* __restrict__ nzbuf,
                         const int* __restrict__ nzcnt,
                         const float* __restrict__ cntF,
                         const float* __restrict__ cntP,
                         float* __restrict__ feat,
                         float* __restrict__ FMpos, float* __restrict__ FPpos) {
    __shared__ int listS[128];
    __shared__ float rS[2][DD];
    __shared__ float posS[2];
    const int row = blockIdx.x, h = blockIdx.y;
    const int tid = threadIdx.x, wv = tid >> 6, lane = tid & 63;
    const float* embX = h ? embP : embM;
    const float* RN = h ? rnP : rnM;
    int K = nzcnt[h * NN + row];
    if (tid < K) listS[tid] = nzbuf[((h * NN + row) << 7) + tid];
    __syncthreads();
    float2 f = reinterpret_cast<const float2*>(Fn + (size_t)row * DD)[lane];
    float2 racc = {0.f, 0.f};
    float wsum = 0.f;
    for (int k = wv; k < K; k += 2) {
        int j = listS[k];
        float rn = RN[j];
        float2 e = reinterpret_cast<const float2*>(embX + (size_t)j * DD)[lane];
        racc.x += e.x;
        racc.y += e.y;
        float d = f.x * e.x + f.y * e.y;
#pragma unroll
        for (int msk = 1; msk <= 32; msk <<= 1) d += __shfl_xor(d, msk);
        wsum += __expf(d * rn * INV_TAU);
    }
    rS[wv][2 * lane] = racc.x;
    rS[wv][2 * lane + 1] = racc.y;
    if (lane == 0) posS[wv] = wsum;
    __syncthreads();
    float cn = (h ? cntP : cntF)[row];
    feat[(size_t)row * (2 * DD) + h * DD + tid] =
        (rS[0][tid] + rS[1][tid]) / fmaxf(cn, 1.0f);
    if (tid == 0) (h ? FPpos : FMpos)[row] = posS[0] + posS[1];
}

// ------- Kernel 5: MLP + softmax + loss (8 rows / 256-thread block) --------
__global__ __launch_bounds__(256) void k_mlp(
        const float* __restrict__ feat,
        const float* __restrict__ W1, const float* __restrict__ b1,
        const float* __restrict__ W2, const float* __restrict__ b2,
        const float* __restrict__ FMpos, const float* __restrict__ FPpos,
        const float* __restrict__ FMtot, const float* __restrict__ FPtot,
        const float* __restrict__ cntF, const float* __restrict__ cntP,
        float* __restrict__ out) {
    __shared__ float featS[8][2 * DD];              // 8 KB
    __shared__ float red[4][4][2];
    __shared__ float lossS[8];
    const int tid = threadIdx.x;
    const int g = tid >> 7, d = tid & 127;
    const int wv = tid >> 6, lane = tid & 63;
    const int row0 = blockIdx.x * 8;
    for (int idx = tid; idx < 8 * 2 * DD; idx += 256)
        featS[idx >> 8][idx & 255] = feat[(size_t)row0 * (2 * DD) + idx];
    __syncthreads();
    float bb = b1[d];
    float acc0 = bb, acc1 = bb, acc2 = bb, acc3 = bb;
    const float* fS = &featS[g * 4][0];
#pragma unroll 4
    for (int c = 0; c < 2 * DD; ++c) {
        float w1v = W1[c * DD + d];
        acc0 = fmaf(fS[0 * 256 + c], w1v, acc0);
        acc1 = fmaf(fS[1 * 256 + c], w1v, acc1);
        acc2 = fmaf(fS[2 * 256 + c], w1v, acc2);
        acc3 = fmaf(fS[3 * 256 + c], w1v, acc3);
    }
    float w20 = W2[2 * d], w21 = W2[2 * d + 1];
    float hr[4] = {fmaxf(acc0, 0.f), fmaxf(acc1, 0.f),
                   fmaxf(acc2, 0.f), fmaxf(acc3, 0.f)};
#pragma unroll
    for (int r = 0; r < 4; ++r) {
        float p0 = hr[r] * w20, p1 = hr[r] * w21;
#pragma unroll
        for (int msk = 1; msk <= 32; msk <<= 1) {
            p0 += __shfl_xor(p0, msk);
            p1 += __shfl_xor(p1, msk);
        }
        if (lane == 0) { red[wv][r][0] = p0; red[wv][r][1] = p1; }
    }
    __syncthreads();
    if (tid < 8) {
        int g2 = tid >> 2, r = tid & 3;
        int row = row0 + tid;
        float z0 = red[2 * g2][r][0] + red[2 * g2 + 1][r][0] + b2[0];
        float z1 = red[2 * g2][r][1] + red[2 * g2 + 1][r][1] + b2[1];
        float mx = fmaxf(z0, z1);
        float e0 = expf(z0 - mx), e1 = expf(z1 - mx);
        float inv = 1.0f / (e0 + e1);
        float w0 = e0 * inv, w1 = e1 * inv;
        out[1 + row * 2 + 0] = w0;
        out[1 + row * 2 + 1] = w1;
        float wp = w0 * FMpos[row] + w1 * FPpos[row];
        float wn = w0 * (FMtot[row] - FMpos[row]) +
                   w1 * (FPtot[row] - FPpos[row]);
        float nei = fmaxf(cntF[row] + cntP[row], 1.0f);
        float ratio = wp / (wp + wn) / nei;
        ratio = fmaxf(ratio, 1e-10f);
        lossS[tid] = -logf(ratio);
    }
    __syncthreads();
    if (tid == 0) {
        float L = 0.f;
#pragma unroll
        for (int r = 0; r < 8; ++r) L += lossS[r];
        atomicAdd(out, L * (1.0f / NN));
    }
}

extern "C" void kernel_launch(void* const* d_in, const int* in_sizes, int n_in,
                              void* d_out, int out_size, void* d_ws, size_t ws_size,
                              hipStream_t stream) {
    const float* embF   = (const float*)d_in[0];
    const float* embM   = (const float*)d_in[1];
    const float* embP   = (const float*)d_in[2];
    const float* FM_adj = (const float*)d_in[3];
    const float* FP_adj = (const float*)d_in[4];
    const float* W1     = (const float*)d_in[5];
    const float* b1     = (const float*)d_in[6];
    const float* W2     = (const float*)d_in[7];
    const float* b2     = (const float*)d_in[8];
    float* out = (float*)d_out;

    float* ws = (float*)d_ws;
    float* FMtot = ws;                       // N  (atomic -> zeroed)
    float* FPtot = FMtot + NN;               // N  (atomic -> zeroed)
    float* FMpos = FPtot + NN;               // N
    float* FPpos = FMpos + NN;               // N
    float* cntF  = FPpos + NN;               // N
    float* cntP  = cntF + NN;                // N
    float* rnM   = cntP + NN;                // N
    float* rnP   = rnM + NN;                 // N
    float* feat  = rnP + NN;                 // N*2D
    float* Fn    = feat + (size_t)NN * 2 * DD;   // N*D fp32 normalized
    __hip_bfloat16* Fnb = (__hip_bfloat16*)(Fn + (size_t)NN * DD);
    __hip_bfloat16* Mnb = Fnb + (size_t)NN * DD;
    __hip_bfloat16* Pnb = Mnb + (size_t)NN * DD;
    int* nzbuf = (int*)(Pnb + (size_t)NN * DD);  // 2*N*128 ints
    int* nzcnt = nzbuf + 2 * (size_t)NN * 128;   // 2*N ints

    hipMemsetAsync(FMtot, 0, 2 * NN * sizeof(float), stream);
    hipMemsetAsync(d_out, 0, sizeof(float), stream);

    k_normalize<<<dim3(NN / 4, 3), 256, 0, stream>>>(embF, embM, embP,
                                                     Fn, rnM, rnP,
                                                     Fnb, Mnb, Pnb);
    k_scan<<<dim3(NN / 4, 2), 256, 0, stream>>>(FM_adj, FP_adj,
                                                nzbuf, nzcnt, cntF, cntP);
    k_dense<<<dim3(NN / 128, 8, 2), 256, 0, stream>>>(Fnb, Mnb, Pnb,
                                                      FMtot, FPtot);
    k_gather<<<dim3(NN, 2), 128, 0, stream>>>(embM, embP, Fn, rnM, rnP,
                                              nzbuf, nzcnt, cntF, cntP,
                                              feat, FMpos, FPpos);
    k_mlp<<<dim3(NN / 8), 256, 0, stream>>>(feat, W1, b1, W2, b2,
                                            FMpos, FPpos, FMtot, FPtot,
                                            cntF, cntP, out);
}

// Round 11
// 391.721 us; speedup vs baseline: 1.4092x; 1.1485x over previous
//
#include <hip/hip_runtime.h>
#include <hip/hip_bf16.h>

#define NN 6144
#define DD 128
#define PBL 136         // padded LDS row stride (bf16 elems) -> balanced banks
#define INV_TAU 10.0f

typedef __attribute__((ext_vector_type(4))) float f32x4;
typedef __attribute__((ext_vector_type(8))) short s16x8;

// ---------------- Kernel 1: L2 normalize -> fp32 Fn, bf16 copies, inv-norms
__global__ void k_normalize(const float* __restrict__ embF,
                            const float* __restrict__ embM,
                            const float* __restrict__ embP,
                            float* __restrict__ Fn,
                            float* __restrict__ rnM, float* __restrict__ rnP,
                            __hip_bfloat16* __restrict__ Fnb,
                            __hip_bfloat16* __restrict__ Mnb,
                            __hip_bfloat16* __restrict__ Pnb) {
    int which = blockIdx.y;
    const float* src = which == 0 ? embF : (which == 1 ? embM : embP);
    __hip_bfloat16* dstb = which == 0 ? Fnb : (which == 1 ? Mnb : Pnb);
    int wave = threadIdx.x >> 6, lane = threadIdx.x & 63;
    int row = blockIdx.x * 4 + wave;
    float2 v = reinterpret_cast<const float2*>(src + (size_t)row * DD)[lane];
    float s = v.x * v.x + v.y * v.y;
#pragma unroll
    for (int m = 1; m <= 32; m <<= 1) s += __shfl_xor(s, m);
    float inv = 1.0f / fmaxf(sqrtf(s), 1e-12f);
    float2 o; o.x = v.x * inv; o.y = v.y * inv;
    if (which == 0)
        reinterpret_cast<float2*>(Fn + (size_t)row * DD)[lane] = o;
    if (lane == 0) {
        if (which == 1) rnM[row] = inv;
        if (which == 2) rnP[row] = inv;
    }
    __hip_bfloat162 ob;
    ob.x = __float2bfloat16(o.x);
    ob.y = __float2bfloat16(o.y);
    reinterpret_cast<__hip_bfloat162*>(dstb + (size_t)row * DD)[lane] = ob;
}

// ------- Kernel 2: fused scan + gather, one block per (row, half) ----------
// Phase A: 256 threads scan the adjacency row (6 strided float4 each),
// compact nnz indices into LDS via per-thread buffers + block prefix.
// Phase B: half-wave (32 lanes x float4 = 128 dims) per neighbor: repr
// partials in registers + exact fp32 pos dot (5-shfl reduce) + exp.
__global__ __launch_bounds__(256) void k_sparse2(
        const float* __restrict__ FM_adj, const float* __restrict__ FP_adj,
        const float* __restrict__ embM, const float* __restrict__ embP,
        const float* __restrict__ Fn,
        const float* __restrict__ rnM, const float* __restrict__ rnP,
        float* __restrict__ feat,
        float* __restrict__ FMpos, float* __restrict__ FPpos,
        float* __restrict__ cntF, float* __restrict__ cntP) {
    __shared__ float FnS[DD];
    __shared__ int lbufT[256][4];            // 4 KB per-thread side buffers
    __shared__ int listS[128];
    __shared__ float reprS[8][DD];           // 4 KB half-wave partials
    __shared__ float posS[8];
    __shared__ int wvS[4];
    __shared__ int Ktot[2];                  // [0] capped K, [1] true total
    const int row = blockIdx.x, h = blockIdx.y;
    const float* adj  = h ? FP_adj : FM_adj;
    const float* embX = h ? embP : embM;
    const float* RN   = h ? rnP : rnM;
    const int tid = threadIdx.x, wv = tid >> 6, lane = tid & 63;

    if (tid < 32)
        reinterpret_cast<float4*>(FnS)[tid] =
            reinterpret_cast<const float4*>(Fn + (size_t)row * DD)[tid];

    // ---- phase A: scan (coalesced, strided so each thread has 6 loads) ----
    const float4* rp = reinterpret_cast<const float4*>(adj + (size_t)row * NN);
    int mycnt = 0;
#pragma unroll
    for (int it = 0; it < 6; ++it) {
        float4 v = rp[it * 256 + tid];
        int cb = (it * 256 + tid) * 4;
        if (v.x != 0.f) { if (mycnt < 4) lbufT[tid][mycnt] = cb;     mycnt++; }
        if (v.y != 0.f) { if (mycnt < 4) lbufT[tid][mycnt] = cb + 1; mycnt++; }
        if (v.z != 0.f) { if (mycnt < 4) lbufT[tid][mycnt] = cb + 2; mycnt++; }
        if (v.w != 0.f) { if (mycnt < 4) lbufT[tid][mycnt] = cb + 3; mycnt++; }
    }
    int cnt = mycnt < 4 ? mycnt : 4;         // P(thread>4 nnz in 24 cols) ~ 0
    int x = cnt;                             // inclusive prefix within wave
#pragma unroll
    for (int d = 1; d < 64; d <<= 1) {
        int y = __shfl_up(x, d);
        if (lane >= d) x += y;
    }
    int t = mycnt;                           // true per-wave total
#pragma unroll
    for (int msk = 1; msk <= 32; msk <<= 1) t += __shfl_xor(t, msk);
    if (tid == 0) Ktot[1] = 0;
    if (lane == 63) wvS[wv] = x;
    __syncthreads();
    if (lane == 0) atomicAdd(&Ktot[1], t);
    if (tid == 0) {
        int s = 0;
#pragma unroll
        for (int i = 0; i < 4; ++i) { int v = wvS[i]; wvS[i] = s; s += v; }
        Ktot[0] = s < 128 ? s : 128;
    }
    __syncthreads();
    int off = wvS[wv] + (x - cnt);
    for (int i = 0; i < cnt; ++i) {
        int s = off + i;
        if (s < 128) listS[s] = lbufT[tid][i];
    }
    __syncthreads();
    const int K = Ktot[0];
    const float trueK = (float)Ktot[1];

    // ---- phase B: gather (half-wave per neighbor) ----
    const int hw = tid >> 5, sl = tid & 31;
    float4 f4 = reinterpret_cast<const float4*>(FnS)[sl];
    float4 racc = {0.f, 0.f, 0.f, 0.f};
    float wsum = 0.f;
    for (int k = hw; k < K; k += 8) {
        int j = listS[k];
        float rn = RN[j];
        float4 e = reinterpret_cast<const float4*>(embX + (size_t)j * DD)[sl];
        racc.x += e.x; racc.y += e.y; racc.z += e.z; racc.w += e.w;
        float d = f4.x * e.x + f4.y * e.y + f4.z * e.z + f4.w * e.w;
#pragma unroll
        for (int msk = 1; msk <= 16; msk <<= 1) d += __shfl_xor(d, msk);
        wsum += __expf(d * rn * INV_TAU);
    }
    reinterpret_cast<float4*>(&reprS[hw][0])[sl] = racc;
    if (sl == 0) posS[hw] = wsum;
    __syncthreads();
    if (tid < DD) {
        float s = 0.f;
#pragma unroll
        for (int i = 0; i < 8; ++i) s += reprS[i][tid];
        feat[(size_t)row * (2 * DD) + h * DD + tid] = s / fmaxf(trueK, 1.0f);
    }
    if (tid == 0) {
        float p = 0.f;
#pragma unroll
        for (int i = 0; i < 8; ++i) p += posS[i];
        (h ? FPpos : FMpos)[row] = p;
        (h ? cntP : cntF)[row] = trueK;
    }
}

// ------- Kernel 3: dense exp row-sum, LDS-staged B, software-pipelined -----
// grid (48, 16, 2), block 256 = 4 waves; wave owns 32 rows (2 frag groups).
__global__ __launch_bounds__(256) void k_dense(
        const __hip_bfloat16* __restrict__ Fnb,
        const __hip_bfloat16* __restrict__ Mnb,
        const __hip_bfloat16* __restrict__ Pnb,
        float* __restrict__ FMtot, float* __restrict__ FPtot) {
    __shared__ __hip_bfloat16 Bs[32][PBL];           // 8704 B, balanced banks
    const int half = blockIdx.z;
    const __hip_bfloat16* Bnb = half ? Pnb : Mnb;
    float* TOT = half ? FPtot : FMtot;
    const int tid = threadIdx.x;
    const int w = tid >> 6, lane = tid & 63;
    const int m = lane & 15, q = lane >> 4;
    const int rb = blockIdx.x * 128 + w * 32;
    const int j0 = blockIdx.y * (NN / 16);           // 384-col strip, 12 iters
    const int srow = tid >> 4, scol = (tid & 15) * 8;

    s16x8 a[2][4];
#pragma unroll
    for (int g = 0; g < 2; ++g)
#pragma unroll
        for (int ks = 0; ks < 4; ++ks)
            a[g][ks] = *reinterpret_cast<const s16x8*>(
                Fnb + (size_t)(rb + g * 16 + m) * DD + ks * 32 + q * 8);

    const float4* gt0 = reinterpret_cast<const float4*>(Bnb + (size_t)j0 * DD);
    float4 s0 = gt0[tid], s1 = gt0[256 + tid];

    float tot[2][4] = {{0.f, 0.f, 0.f, 0.f}, {0.f, 0.f, 0.f, 0.f}};
    for (int it = 0; it < 12; ++it) {
        __syncthreads();                 // previous tile fully consumed
        *reinterpret_cast<float4*>(&Bs[srow][scol]) = s0;
        *reinterpret_cast<float4*>(&Bs[16 + srow][scol]) = s1;
        __syncthreads();                 // tile visible to all waves
        if (it + 1 < 12) {
            const float4* gt = reinterpret_cast<const float4*>(
                Bnb + (size_t)(j0 + (it + 1) * 32) * DD);
            s0 = gt[tid];
            s1 = gt[256 + tid];
        }
        asm volatile("" ::: "memory");
        s16x8 b[2][4];
#pragma unroll
        for (int t = 0; t < 2; ++t)
#pragma unroll
            for (int ks = 0; ks < 4; ++ks)
                b[t][ks] = *reinterpret_cast<const s16x8*>(
                    &Bs[t * 16 + m][ks * 32 + q * 8]);
#pragma unroll
        for (int g = 0; g < 2; ++g)
#pragma unroll
            for (int t = 0; t < 2; ++t) {
                f32x4 acc = {0.f, 0.f, 0.f, 0.f};
#pragma unroll
                for (int ks = 0; ks < 4; ++ks)
                    acc = __builtin_amdgcn_mfma_f32_16x16x32_bf16(
                        a[g][ks], b[t][ks], acc, 0, 0, 0);
#pragma unroll
                for (int r = 0; r < 4; ++r)
                    tot[g][r] += __expf(acc[r] * INV_TAU);
            }
    }
#pragma unroll
    for (int msk = 1; msk <= 8; msk <<= 1)
#pragma unroll
        for (int g = 0; g < 2; ++g)
#pragma unroll
            for (int r = 0; r < 4; ++r)
                tot[g][r] += __shfl_xor(tot[g][r], msk);
    if (m == 0)
#pragma unroll
        for (int g = 0; g < 2; ++g)
#pragma unroll
            for (int r = 0; r < 4; ++r)
                atomicAdd(&TOT[rb + g * 16 + q * 4 + r], tot[g][r]);
}

// ------- Kernel 4: MLP + softmax + loss (8 rows / 256-thread block) --------
// 2 threads per output dim (c-range split) halves the serial W1-load chain.
__global__ __launch_bounds__(256) void k_mlp(
        const float* __restrict__ feat,
        const float* __restrict__ W1, const float* __restrict__ b1,
        const float* __restrict__ W2, const float* __restrict__ b2,
        const float* __restrict__ FMpos, const float* __restrict__ FPpos,
        const float* __restrict__ FMtot, const float* __restrict__ FPtot,
        const float* __restrict__ cntF, const float* __restrict__ cntP,
        float* __restrict__ out) {
    __shared__ float featS[8][2 * DD];               // 8 KB
    __shared__ float partS[2][8][DD];                // 8 KB
    __shared__ float redS[2][8][2];
    __shared__ float lossS[8];
    const int tid = threadIdx.x;
    const int cp = tid >> 7, d = tid & 127;
    const int row0 = blockIdx.x * 8;
    for (int idx = tid; idx < 8 * 2 * DD; idx += 256)
        featS[idx >> 8][idx & 255] = feat[(size_t)row0 * (2 * DD) + idx];
    __syncthreads();
    float bb = (cp == 0) ? b1[d] : 0.f;
    float acc[8];
#pragma unroll
    for (int r = 0; r < 8; ++r) acc[r] = bb;
    const int c0 = cp * 128;
    for (int c = c0; c < c0 + 128; c += 2) {
        float wA = W1[c * DD + d];
        float wB = W1[(c + 1) * DD + d];
#pragma unroll
        for (int r = 0; r < 8; ++r)
            acc[r] = fmaf(featS[r][c + 1], wB, fmaf(featS[r][c], wA, acc[r]));
    }
#pragma unroll
    for (int r = 0; r < 8; ++r) partS[cp][r][d] = acc[r];
    __syncthreads();
    if (tid < 128) {
        const int lane = tid & 63, wv = tid >> 6;
        float w20 = W2[2 * tid], w21 = W2[2 * tid + 1];
        float p0s[8], p1s[8];
#pragma unroll
        for (int r = 0; r < 8; ++r) {
            float hh = fmaxf(partS[0][r][tid] + partS[1][r][tid], 0.f);
            p0s[r] = hh * w20;
            p1s[r] = hh * w21;
        }
#pragma unroll
        for (int r = 0; r < 8; ++r)
#pragma unroll
            for (int msk = 1; msk <= 32; msk <<= 1) {
                p0s[r] += __shfl_xor(p0s[r], msk);
                p1s[r] += __shfl_xor(p1s[r], msk);
            }
        if (lane == 0)
#pragma unroll
            for (int r = 0; r < 8; ++r) {
                redS[wv][r][0] = p0s[r];
                redS[wv][r][1] = p1s[r];
            }
    }
    __syncthreads();
    if (tid < 8) {
        int row = row0 + tid;
        float z0 = redS[0][tid][0] + redS[1][tid][0] + b2[0];
        float z1 = redS[0][tid][1] + redS[1][tid][1] + b2[1];
        float mx = fmaxf(z0, z1);
        float e0 = expf(z0 - mx), e1 = expf(z1 - mx);
        float inv = 1.0f / (e0 + e1);
        float w0 = e0 * inv, w1 = e1 * inv;
        out[1 + row * 2 + 0] = w0;
        out[1 + row * 2 + 1] = w1;
        float wp = w0 * FMpos[row] + w1 * FPpos[row];
        float wn = w0 * (FMtot[row] - FMpos[row]) +
                   w1 * (FPtot[row] - FPpos[row]);
        float nei = fmaxf(cntF[row] + cntP[row], 1.0f);
        float ratio = wp / (wp + wn) / nei;
        ratio = fmaxf(ratio, 1e-10f);
        lossS[tid] = -logf(ratio);
    }
    __syncthreads();
    if (tid == 0) {
        float L = 0.f;
#pragma unroll
        for (int r = 0; r < 8; ++r) L += lossS[r];
        atomicAdd(out, L * (1.0f / NN));
    }
}

extern "C" void kernel_launch(void* const* d_in, const int* in_sizes, int n_in,
                              void* d_out, int out_size, void* d_ws, size_t ws_size,
                              hipStream_t stream) {
    const float* embF   = (const float*)d_in[0];
    const float* embM   = (const float*)d_in[1];
    const float* embP   = (const float*)d_in[2];
    const float* FM_adj = (const float*)d_in[3];
    const float* FP_adj = (const float*)d_in[4];
    const float* W1     = (const float*)d_in[5];
    const float* b1     = (const float*)d_in[6];
    const float* W2     = (const float*)d_in[7];
    const float* b2     = (const float*)d_in[8];
    float* out = (float*)d_out;

    float* ws = (float*)d_ws;
    float* FMtot = ws;                       // N  (atomic -> zeroed)
    float* FPtot = FMtot + NN;               // N  (atomic -> zeroed)
    float* FMpos = FPtot + NN;               // N
    float* FPpos = FMpos + NN;               // N
    float* cntF  = FPpos + NN;               // N
    float* cntP  = cntF + NN;                // N
    float* rnM   = cntP + NN;                // N
    float* rnP   = rnM + NN;                 // N
    float* feat  = rnP + NN;                 // N*2D
    float* Fn    = feat + (size_t)NN * 2 * DD;   // N*D fp32 normalized
    __hip_bfloat16* Fnb = (__hip_bfloat16*)(Fn + (size_t)NN * DD);
    __hip_bfloat16* Mnb = Fnb + (size_t)NN * DD;
    __hip_bfloat16* Pnb = Mnb + (size_t)NN * DD;

    hipMemsetAsync(FMtot, 0, 2 * NN * sizeof(float), stream);
    hipMemsetAsync(d_out, 0, sizeof(float), stream);

    k_normalize<<<dim3(NN / 4, 3), 256, 0, stream>>>(embF, embM, embP,
                                                     Fn, rnM, rnP,
                                                     Fnb, Mnb, Pnb);
    k_sparse2<<<dim3(NN, 2), 256, 0, stream>>>(FM_adj, FP_adj, embM, embP,
                                               Fn, rnM, rnP, feat,
                                               FMpos, FPpos, cntF, cntP);
    k_dense<<<dim3(NN / 128, 16, 2), 256, 0, stream>>>(Fnb, Mnb, Pnb,
                                                       FMtot, FPtot);
    k_mlp<<<dim3(NN / 8), 256, 0, stream>>>(feat, W1, b1, W2, b2,
                                            FMpos, FPpos, FMtot, FPtot,
                                            cntF, cntP, out);
}